// Round 7
// baseline (16366.866 us; speedup 1.0000x reference)
//
#include <hip/hip_runtime.h>
#include <math.h>

// Problem constants
#define BATCH  256
#define SEQT   256
#define FEATD  256
#define NHEADS 8
#define HD     32
#define HID    512
#define GATES  2048
#define BH     (BATCH*HID)       // halves per h plane parity slab
#define TOUT   (SEQT-1)
#define NBLK   256
#define THR    1024
#define DEPTH  4                 // prefetch depth (slices)

typedef __attribute__((ext_vector_type(8))) short short8;
typedef __attribute__((ext_vector_type(4))) float f32x4;
typedef unsigned short u16;

union U8 { uint4 u4; short8 s8; };

__device__ __forceinline__ float sigm(float x)     { return 1.f / (1.f + __expf(-x)); }
__device__ __forceinline__ float tanhfast(float x) { return 1.f - 2.f / (1.f + __expf(2.f * x)); }

__device__ __forceinline__ u16 bf16rn(float f) {
    union { float f; unsigned u; } v; v.f = f;
    unsigned r = v.u + 0x7fffu + ((v.u >> 16) & 1u);
    return (u16)(r >> 16);
}
__device__ __forceinline__ float bf2f(u16 h) {
    union { float f; unsigned u; } v; v.u = ((unsigned)h) << 16; return v.f;
}

// ---------------------------------------------------------------------------
// Fused per-(n,h) attention (verified). Output T-major CB8 layout:
// attn[t][cb8=f/8][n][8] split bf16 hi/lo planes (65536 halves per t-slice).
// ---------------------------------------------------------------------------
__global__ __launch_bounds__(256) void k_attn(
    const float* __restrict__ x,  const float* __restrict__ wq,
    const float* __restrict__ wk, const float* __restrict__ wv,
    u16* __restrict__ attnH, u16* __restrict__ attnL)
{
    __shared__ float Ks[128][40];
    __shared__ float Vs[128][40];

    const int nb  = blockIdx.x;
    const int n   = nb >> 3, h = nb & 7;
    const int tid = threadIdx.x;
    const float* xbase = x + ((size_t)n * SEQT) * FEATD + h * HD;

    float qv[HD];
    {
        float xr[HD];
        const float4* xp = (const float4*)(xbase + (size_t)tid * FEATD);
        #pragma unroll
        for (int q4 = 0; q4 < 8; ++q4) {
            float4 v = xp[q4];
            xr[q4*4+0] = v.x; xr[q4*4+1] = v.y; xr[q4*4+2] = v.z; xr[q4*4+3] = v.w;
        }
        #pragma unroll
        for (int d = 0; d < HD; ++d) {
            float s = 0.f;
            #pragma unroll
            for (int e = 0; e < HD; ++e) s += xr[e] * wq[d*HD + e];
            qv[d] = s * 0.0625f;
        }
    }

    float o[HD];
    #pragma unroll
    for (int d = 0; d < HD; ++d) o[d] = 0.f;
    float m = -1e30f, ssum = 0.f;

    for (int tile = 0; tile < 2; ++tile) {
        const int j0 = tile * 128;
        __syncthreads();
        {
            const int r = tid & 127;
            const float* W = (tid < 128) ? wk : wv;
            float xt[HD];
            const float4* xp = (const float4*)(xbase + (size_t)(j0 + r) * FEATD);
            #pragma unroll
            for (int q4 = 0; q4 < 8; ++q4) {
                float4 v = xp[q4];
                xt[q4*4+0] = v.x; xt[q4*4+1] = v.y; xt[q4*4+2] = v.z; xt[q4*4+3] = v.w;
            }
            float outr[HD];
            #pragma unroll
            for (int d = 0; d < HD; ++d) {
                float s = 0.f;
                #pragma unroll
                for (int e = 0; e < HD; ++e) s += xt[e] * W[d*HD + e];
                outr[d] = s;
            }
            float (*dst)[40] = (tid < 128) ? Ks : Vs;
            #pragma unroll
            for (int d = 0; d < HD; ++d) dst[r][d] = outr[d];
        }
        __syncthreads();

        for (int j = 0; j < 128; ++j) {
            float e = 0.f;
            #pragma unroll
            for (int dq = 0; dq < 8; ++dq) {
                float4 kq = *(const float4*)&Ks[j][dq*4];
                e += qv[dq*4+0]*kq.x + qv[dq*4+1]*kq.y
                   + qv[dq*4+2]*kq.z + qv[dq*4+3]*kq.w;
            }
            if (e > m) {
                float sc = __expf(m - e);
                ssum *= sc;
                #pragma unroll
                for (int d = 0; d < HD; ++d) o[d] *= sc;
                m = e;
            }
            float p = __expf(e - m);
            ssum += p;
            #pragma unroll
            for (int dq = 0; dq < 8; ++dq) {
                float4 vq = *(const float4*)&Vs[j][dq*4];
                o[dq*4+0] += p * vq.x; o[dq*4+1] += p * vq.y;
                o[dq*4+2] += p * vq.z; o[dq*4+3] += p * vq.w;
            }
        }
    }

    const float inv = 1.f / ssum;
    #pragma unroll
    for (int dq = 0; dq < 8; ++dq) {
        ushort4 vh, vl;
        float v0 = o[dq*4+0]*inv, v1 = o[dq*4+1]*inv,
              v2 = o[dq*4+2]*inv, v3 = o[dq*4+3]*inv;
        u16 a0 = bf16rn(v0); vh.x = a0; vl.x = bf16rn(v0 - bf2f(a0));
        u16 a1 = bf16rn(v1); vh.y = a1; vl.y = bf16rn(v1 - bf2f(a1));
        u16 a2 = bf16rn(v2); vh.z = a2; vl.z = bf16rn(v2 - bf2f(a2));
        u16 a3 = bf16rn(v3); vh.w = a3; vl.w = bf16rn(v3 - bf2f(a3));
        const size_t a = (size_t)tid*65536
                       + (size_t)(h*4 + (dq >> 1))*2048
                       + (size_t)n*8 + (dq & 1)*4;
        *(ushort4*)(attnH + a) = vh;
        *(ushort4*)(attnL + a) = vl;
    }
}

// ---------------------------------------------------------------------------
// Wc = w_hid @ w_fc [512,256]; bc = w_hid @ b_fc + b_hid  (verified)
// ---------------------------------------------------------------------------
__global__ __launch_bounds__(256) void k_wcomb(
    const float* __restrict__ w_fc,  const float* __restrict__ b_fc,
    const float* __restrict__ w_hid, const float* __restrict__ b_hid,
    float* __restrict__ Wc, float* __restrict__ bc)
{
    const int i = blockIdx.x, j = threadIdx.x;
    float s = 0.f;
    for (int k = 0; k < FEATD; ++k) s += w_hid[i*FEATD + k] * w_fc[k*FEATD + j];
    Wc[(size_t)i*FEATD + j] = s;
    if (j == 0) {
        float t = b_hid[i];
        for (int k = 0; k < FEATD; ++k) t += w_hid[i*FEATD + k] * b_fc[k];
        bc[i] = t;
    }
}

// ---------------------------------------------------------------------------
// Wx0 = W_ih[0] @ Wc [2048,256]; bx0 = W_ih[0] @ bc + b_ih[0] + b_hh[0]
// ---------------------------------------------------------------------------
__global__ __launch_bounds__(256) void k_wx0(
    const float* __restrict__ w_ih, const float* __restrict__ Wc,
    const float* __restrict__ bc,   const float* __restrict__ b_ih,
    const float* __restrict__ b_hh,
    float* __restrict__ Wx0, float* __restrict__ bx0)
{
    const int i = blockIdx.x, j = threadIdx.x;
    float s = 0.f;
    for (int k = 0; k < HID; ++k) s += w_ih[(size_t)i*HID + k] * Wc[(size_t)k*FEATD + j];
    Wx0[(size_t)i*FEATD + j] = s;
    if (j == 0) {
        float t = b_ih[i] + b_hh[i];
        for (int k = 0; k < HID; ++k) t += w_ih[(size_t)i*HID + k] * bc[k];
        bx0[i] = t;
    }
}

// ---------------------------------------------------------------------------
// Pre-pack weights into MFMA B-fragment order, split bf16 hi/lo.
// Block = (layer, tile tl in [0,128)): cg=tl>>4, n=tl&15, g=n>>2, cs=n&3.
// Tile covers gate-cols col(l) = g*512 + cg*64 + cs*16 + (l&15).
// dst[e]: e = s*512 + l*8 + j -> W[col(l)][k = s*32 + (l>>4)*8 + j].
// Layer1 K=1024 = [Wih1|Whh1] (32 slices); Layer0 K=768 = [Wx0|Whh0] (24).
// ---------------------------------------------------------------------------
__global__ __launch_bounds__(256) void k_pack(
    const float* __restrict__ w_ih, const float* __restrict__ w_hh,
    const float* __restrict__ Wx0,
    u16* __restrict__ wp1H, u16* __restrict__ wp1L,
    u16* __restrict__ wp0H, u16* __restrict__ wp0L)
{
    const int bx = blockIdx.x;
    const bool lay1 = (bx < 128);
    const int tl = bx & 127;
    const int cg = tl >> 4, n = tl & 15;
    const int colbase = (n >> 2)*512 + cg*64 + (n & 3)*16;
    const int NS = lay1 ? 32 : 24;
    u16* dH = lay1 ? wp1H + (size_t)tl*32*512 : wp0H + (size_t)tl*24*512;
    u16* dL = lay1 ? wp1L + (size_t)tl*32*512 : wp0L + (size_t)tl*24*512;
    const float* wih1 = w_ih + (size_t)GATES*HID;
    const float* whh1 = w_hh + (size_t)GATES*HID;

    for (int e = threadIdx.x; e < NS*512; e += 256) {
        const int s = e >> 9, li = (e >> 3) & 63, j = e & 7;
        const int col = colbase + (li & 15);
        const int k = s*32 + ((li >> 4) << 3) + j;
        float f;
        if (lay1) f = (k < 512) ? wih1[(size_t)col*HID + k]
                                : whh1[(size_t)col*HID + (k - 512)];
        else      f = (k < 256) ? Wx0[(size_t)col*FEATD + k]
                                : w_hh[(size_t)col*HID + (k - 256)];
        const u16 hi = bf16rn(f);
        dH[e] = hi;
        dL[e] = bf16rn(f - bf2f(hi));
    }
}

// ---------------------------------------------------------------------------
// Device-scope grid barrier (verified mechanism, rounds 3-6).
// ---------------------------------------------------------------------------
__device__ __forceinline__ void grid_bar(int* bar, int target)
{
    __syncthreads();
    if (threadIdx.x == 0) {
        __threadfence();
        __hip_atomic_fetch_add(bar, 1, __ATOMIC_RELEASE, __HIP_MEMORY_SCOPE_AGENT);
        while (__hip_atomic_load(bar, __ATOMIC_RELAXED, __HIP_MEMORY_SCOPE_AGENT) < target)
            __builtin_amdgcn_s_sleep(2);
        __threadfence();
    }
    __syncthreads();
}

// ---------------------------------------------------------------------------
struct Geo {
    const u16* wbH; const u16* wbL;   // packed weights for this wave's tile
    float* Cb;                        // LDS C bounce [16][257]
    int aoff;                         // A frag offset = aq*2048 + rowg*8
    int boff;                         // B frag offset = l*8
    int wid, l;                       // wave, lane
    int erow, hcl;                    // epilogue row (0..15) / h-col (0..63)
    int cg, mg;
    float bsum[4];
};

// One LSTM step. A = [s0 (NT0 slices) | s1], NT slices total (K=NT*32).
// A from CB8 global layout; B from packed global; 3-term split-fp32 MFMA.
template<int NT0, int NT>
__device__ __forceinline__ void do_step(
    const Geo& G,
    const u16* __restrict__ s0H, const u16* __restrict__ s0L,
    const u16* __restrict__ s1H, const u16* __restrict__ s1L,
    u16* __restrict__ dH, u16* __restrict__ dL, float& cr)
{
    uint4 pAh[DEPTH], pAl[DEPTH], pBh[DEPTH], pBl[DEPTH];

    auto ld = [&](int d, int s) {
        const u16* pH; const u16* pL; int sl;
        if (s < NT0) { pH = s0H; pL = s0L; sl = s; }
        else         { pH = s1H; pL = s1L; sl = s - NT0; }
        const size_t a = (size_t)sl*8192 + G.aoff;
        pAh[d] = *(const uint4*)(pH + a);
        pAl[d] = *(const uint4*)(pL + a);
        const size_t b = (size_t)s*512 + G.boff;
        pBh[d] = *(const uint4*)(G.wbH + b);
        pBl[d] = *(const uint4*)(G.wbL + b);
    };

    constexpr int PR = (DEPTH < NT) ? DEPTH : NT;
    #pragma unroll
    for (int d = 0; d < PR; ++d) ld(d, d);

    f32x4 acc = {0.f, 0.f, 0.f, 0.f};
    #pragma unroll
    for (int s = 0; s < NT; ++s) {
        U8 ah, al, bh, bl;
        ah.u4 = pAh[s % DEPTH]; al.u4 = pAl[s % DEPTH];
        bh.u4 = pBh[s % DEPTH]; bl.u4 = pBl[s % DEPTH];
        if (s + DEPTH < NT) ld(s % DEPTH, s + DEPTH);
        acc = __builtin_amdgcn_mfma_f32_16x16x32_bf16(ah.s8, bh.s8, acc, 0,0,0);
        acc = __builtin_amdgcn_mfma_f32_16x16x32_bf16(al.s8, bh.s8, acc, 0,0,0);
        acc = __builtin_amdgcn_mfma_f32_16x16x32_bf16(ah.s8, bl.s8, acc, 0,0,0);
    }

    // C tile -> LDS bounce: Cb[row(0..15)][lc = wid*16 + (l&15)]
    {
        const int crow = (G.l >> 4) * 4;
        const int ccol = G.wid*16 + (G.l & 15);
        #pragma unroll
        for (int r = 0; r < 4; ++r)
            G.Cb[(crow + r)*257 + ccol] = acc[r];
    }
    __syncthreads();

    // epilogue: thread -> (erow, hcl); local col for gate g = g*64 + hcl
    {
        float g4[4];
        #pragma unroll
        for (int g = 0; g < 4; ++g)
            g4[g] = G.Cb[G.erow*257 + g*64 + G.hcl] + G.bsum[g];
        const float gi = sigm(g4[0]), gf = sigm(g4[1]);
        const float gg = tanhfast(g4[2]), go = sigm(g4[3]);
        cr = gf*cr + gi*gg;
        const float h = go * tanhfast(cr);
        const u16 hh = bf16rn(h);
        const u16 hl = bf16rn(h - bf2f(hh));
        const size_t a = (size_t)(G.cg*8 + (G.hcl >> 3))*2048
                       + (size_t)(G.mg*16 + G.erow)*8 + (G.hcl & 7);
        dH[a] = hh; dL[a] = hl;
    }
}

// ---------------------------------------------------------------------------
// Persistent MFMA LSTM. 256 blocks x 1024 threads (16 waves, 4/SIMD).
// Layer 1: blocks 0..127; layer 0: 128..255. Block = (mg 0..15, cg 0..7):
// 256 gate-cols (4 gates x 64 h-cols [cg*64..)) x 16 rows [mg*16..).
// blockIdx = 128*L + mg*8 + cg -> XCD = cg: the 16 mg-blocks sharing a cg's
// weight set co-reside on one XCD (L2 locality). Weights streamed from the
// k_pack fragment layout; LDS = 16.4 KB C bounce only.
// ---------------------------------------------------------------------------
__global__ __launch_bounds__(THR, 1) void k_lstm(
    const u16* __restrict__ attnH, const u16* __restrict__ attnL,
    const u16* __restrict__ wp1H, const u16* __restrict__ wp1L,
    const u16* __restrict__ wp0H, const u16* __restrict__ wp0L,
    const float* __restrict__ bx0,
    u16* __restrict__ h0h, u16* __restrict__ h0l,
    u16* __restrict__ h1h, u16* __restrict__ h1l,
    const float* __restrict__ b_ih, const float* __restrict__ b_hh,
    const float* __restrict__ w_out, const float* __restrict__ b_out,
    float* __restrict__ out, int* __restrict__ bar)
{
    __shared__ float Cb[16*257];
    const int tid = threadIdx.x;
    const int bx  = blockIdx.x;
    const bool lay1 = (bx < 128);
    const int idx = lay1 ? bx : bx - 128;
    const int mg = idx >> 3, cg = idx & 7;
    const int wid = tid >> 6, l = tid & 63;

    Geo G;
    G.Cb = Cb;
    G.wid = wid; G.l = l;
    G.aoff = (l >> 4)*2048 + (mg*16 + (l & 15))*8;
    G.boff = l*8;
    {
        const int wtile = cg*16 + wid;
        G.wbH = lay1 ? wp1H + (size_t)wtile*32*512 : wp0H + (size_t)wtile*24*512;
        G.wbL = lay1 ? wp1L + (size_t)wtile*32*512 : wp0L + (size_t)wtile*24*512;
    }
    G.erow = tid >> 6; G.hcl = tid & 63;
    G.cg = cg; G.mg = mg;
    #pragma unroll
    for (int g = 0; g < 4; ++g) {
        const int gidx = g*HID + cg*64 + G.hcl;
        G.bsum[g] = lay1 ? (b_ih[GATES + gidx] + b_hh[GATES + gidx]) : bx0[gidx];
    }
    float cr = 0.f;

    // projection: rows 2*idx, 2*idx+1 (layer-0 blocks only)
    auto proj = [&](const u16* hH, const u16* hL, int tout) {
        if (tid < 256) {
            const int r = tid >> 7, j = (tid >> 4) & 7, ks = tid & 15;
            const int n = 2*idx + r;
            float s = 0.f;
            #pragma unroll
            for (int kk = 0; kk < 32; ++kk) {
                const int k = ks*32 + kk;
                const size_t a = (size_t)(k >> 3)*2048 + (size_t)n*8 + (k & 7);
                float hv = bf2f(hH[a]) + bf2f(hL[a]);
                hv = hv > 0.f ? hv : 0.f;
                s += hv * w_out[(size_t)j*HID + k];
            }
            s += __shfl_xor(s, 1); s += __shfl_xor(s, 2);
            s += __shfl_xor(s, 4); s += __shfl_xor(s, 8);
            if (ks == 0)
                out[(size_t)n*(TOUT*NHEADS) + (size_t)tout*NHEADS + j] = s + b_out[j];
        }
    };

    // ---- prologue: layer0 computes h0(0) from attn(0) only
    if (!lay1)
        do_step<8,8>(G, attnH, attnL, attnH, attnL, h0h, h0l, cr);
    grid_bar(bar, 1*NBLK);

    // ---- pipelined: layer1(t) || layer0(t+1), t = 0..254
    for (int t = 0; t <= SEQT - 2; ++t) {
        if (lay1) {
            const int p = t & 1, q = p ^ 1;
            if (t == 0)
                do_step<16,16>(G, h0h + (size_t)p*BH, h0l + (size_t)p*BH,
                                  h1h + (size_t)q*BH, h1l + (size_t)q*BH,
                                  h1h + (size_t)p*BH, h1l + (size_t)p*BH, cr);
            else
                do_step<16,32>(G, h0h + (size_t)p*BH, h0l + (size_t)p*BH,
                                  h1h + (size_t)q*BH, h1l + (size_t)q*BH,
                                  h1h + (size_t)p*BH, h1l + (size_t)p*BH, cr);
        } else {
            if (t >= 1) {
                const int q = (t - 1) & 1;
                proj(h1h + (size_t)q*BH, h1l + (size_t)q*BH, t - 1);
            }
            if (t <= SEQT - 3) {
                const int tt = t + 1, p = t & 1, d = tt & 1;
                do_step<8,24>(G, attnH + (size_t)tt*65536, attnL + (size_t)tt*65536,
                                 h0h + (size_t)p*BH, h0l + (size_t)p*BH,
                                 h0h + (size_t)d*BH, h0l + (size_t)d*BH, cr);
            }
        }
        grid_bar(bar, (t + 2)*NBLK);
    }

    // ---- tail: project h1(254) (parity 0)
    if (!lay1) proj(h1h, h1l, TOUT - 1);
}

// ---------------------------------------------------------------------------
extern "C" void kernel_launch(void* const* d_in, const int* in_sizes, int n_in,
                              void* d_out, int out_size, void* d_ws, size_t ws_size,
                              hipStream_t stream)
{
    (void)in_sizes; (void)n_in; (void)out_size; (void)ws_size;
    const float* x     = (const float*)d_in[0];
    const float* wq    = (const float*)d_in[1];
    const float* wk    = (const float*)d_in[2];
    const float* wv    = (const float*)d_in[3];
    const float* w_fc  = (const float*)d_in[4];
    const float* b_fc  = (const float*)d_in[5];
    const float* w_hid = (const float*)d_in[6];
    const float* b_hid = (const float*)d_in[7];
    const float* w_ih  = (const float*)d_in[8];
    const float* w_hh  = (const float*)d_in[9];
    const float* b_ih  = (const float*)d_in[10];
    const float* b_hh  = (const float*)d_in[11];
    const float* w_out = (const float*)d_in[12];
    const float* b_out = (const float*)d_in[13];

    float* ws = (float*)d_ws;
    size_t off = 0;
    u16* attnH = (u16*)(ws + off); off += (size_t)SEQT*BATCH*FEATD/2;
    u16* attnL = (u16*)(ws + off); off += (size_t)SEQT*BATCH*FEATD/2;
    float* Wc  = ws + off; off += (size_t)HID*FEATD;
    float* bc  = ws + off; off += HID;
    float* Wx0 = ws + off; off += (size_t)GATES*FEATD;
    float* bx0 = ws + off; off += GATES;
    u16* h0h = (u16*)(ws + off); off += BH;      // 2 parity slabs (BH halves)
    u16* h0l = (u16*)(ws + off); off += BH;
    u16* h1h = (u16*)(ws + off); off += BH;
    u16* h1l = (u16*)(ws + off); off += BH;
    u16* wp1H = (u16*)(ws + off); off += (size_t)128*32*512/2;   // 2.1M halves
    u16* wp1L = (u16*)(ws + off); off += (size_t)128*32*512/2;
    u16* wp0H = (u16*)(ws + off); off += (size_t)128*24*512/2;   // 1.57M halves
    u16* wp0L = (u16*)(ws + off); off += (size_t)128*24*512/2;
    int* bar = (int*)(ws + off); off += 64;
    // total ~22.3M floats = ~89 MB

    hipMemsetAsync(bar, 0, sizeof(int), stream);

    k_attn  <<<dim3(BATCH*NHEADS), dim3(256), 0, stream>>>(x, wq, wk, wv, attnH, attnL);
    k_wcomb <<<dim3(HID),          dim3(256), 0, stream>>>(w_fc, b_fc, w_hid, b_hid, Wc, bc);
    k_wx0   <<<dim3(GATES),        dim3(256), 0, stream>>>(w_ih, Wc, bc, b_ih, b_hh, Wx0, bx0);
    k_pack  <<<dim3(256),          dim3(256), 0, stream>>>(w_ih, w_hh, Wx0,
                                                           wp1H, wp1L, wp0H, wp0L);

    k_lstm <<<dim3(NBLK), dim3(THR), 0, stream>>>(
        attnH, attnL, wp1H, wp1L, wp0H, wp0L, bx0,
        h0h, h0l, h1h, h1l, b_ih, b_hh, w_out, b_out, (float*)d_out, bar);
}

// Round 8
// 16276.863 us; speedup vs baseline: 1.0055x; 1.0055x over previous
//
#include <hip/hip_runtime.h>
#include <math.h>

// Problem constants
#define BATCH  256
#define SEQT   256
#define FEATD  256
#define NHEADS 8
#define HD     32
#define HID    512
#define GATES  2048
#define BH     (BATCH*HID)       // halves per h plane parity slab
#define TOUT   (SEQT-1)
#define NBLK   256
#define THR    1024
#define DEPTH  6                 // prefetch depth (slices)

typedef __attribute__((ext_vector_type(8))) short short8;
typedef __attribute__((ext_vector_type(4))) float f32x4;
typedef unsigned short u16;

union U8 { uint4 u4; short8 s8; };

__device__ __forceinline__ float sigm(float x)     { return 1.f / (1.f + __expf(-x)); }
__device__ __forceinline__ float tanhfast(float x) { return 1.f - 2.f / (1.f + __expf(2.f * x)); }

__device__ __forceinline__ u16 bf16rn(float f) {
    union { float f; unsigned u; } v; v.f = f;
    unsigned r = v.u + 0x7fffu + ((v.u >> 16) & 1u);
    return (u16)(r >> 16);
}
__device__ __forceinline__ float bf2f(u16 h) {
    union { float f; unsigned u; } v; v.u = ((unsigned)h) << 16; return v.f;
}

// ---------------------------------------------------------------------------
// Fused per-(n,h) attention (verified). Output T-major CB8 layout:
// attn[t][cb8=f/8][n][8] split bf16 hi/lo planes (65536 halves per t-slice).
// ---------------------------------------------------------------------------
__global__ __launch_bounds__(256) void k_attn(
    const float* __restrict__ x,  const float* __restrict__ wq,
    const float* __restrict__ wk, const float* __restrict__ wv,
    u16* __restrict__ attnH, u16* __restrict__ attnL)
{
    __shared__ float Ks[128][40];
    __shared__ float Vs[128][40];

    const int nb  = blockIdx.x;
    const int n   = nb >> 3, h = nb & 7;
    const int tid = threadIdx.x;
    const float* xbase = x + ((size_t)n * SEQT) * FEATD + h * HD;

    float qv[HD];
    {
        float xr[HD];
        const float4* xp = (const float4*)(xbase + (size_t)tid * FEATD);
        #pragma unroll
        for (int q4 = 0; q4 < 8; ++q4) {
            float4 v = xp[q4];
            xr[q4*4+0] = v.x; xr[q4*4+1] = v.y; xr[q4*4+2] = v.z; xr[q4*4+3] = v.w;
        }
        #pragma unroll
        for (int d = 0; d < HD; ++d) {
            float s = 0.f;
            #pragma unroll
            for (int e = 0; e < HD; ++e) s += xr[e] * wq[d*HD + e];
            qv[d] = s * 0.0625f;
        }
    }

    float o[HD];
    #pragma unroll
    for (int d = 0; d < HD; ++d) o[d] = 0.f;
    float m = -1e30f, ssum = 0.f;

    for (int tile = 0; tile < 2; ++tile) {
        const int j0 = tile * 128;
        __syncthreads();
        {
            const int r = tid & 127;
            const float* W = (tid < 128) ? wk : wv;
            float xt[HD];
            const float4* xp = (const float4*)(xbase + (size_t)(j0 + r) * FEATD);
            #pragma unroll
            for (int q4 = 0; q4 < 8; ++q4) {
                float4 v = xp[q4];
                xt[q4*4+0] = v.x; xt[q4*4+1] = v.y; xt[q4*4+2] = v.z; xt[q4*4+3] = v.w;
            }
            float outr[HD];
            #pragma unroll
            for (int d = 0; d < HD; ++d) {
                float s = 0.f;
                #pragma unroll
                for (int e = 0; e < HD; ++e) s += xt[e] * W[d*HD + e];
                outr[d] = s;
            }
            float (*dst)[40] = (tid < 128) ? Ks : Vs;
            #pragma unroll
            for (int d = 0; d < HD; ++d) dst[r][d] = outr[d];
        }
        __syncthreads();

        for (int j = 0; j < 128; ++j) {
            float e = 0.f;
            #pragma unroll
            for (int dq = 0; dq < 8; ++dq) {
                float4 kq = *(const float4*)&Ks[j][dq*4];
                e += qv[dq*4+0]*kq.x + qv[dq*4+1]*kq.y
                   + qv[dq*4+2]*kq.z + qv[dq*4+3]*kq.w;
            }
            if (e > m) {
                float sc = __expf(m - e);
                ssum *= sc;
                #pragma unroll
                for (int d = 0; d < HD; ++d) o[d] *= sc;
                m = e;
            }
            float p = __expf(e - m);
            ssum += p;
            #pragma unroll
            for (int dq = 0; dq < 8; ++dq) {
                float4 vq = *(const float4*)&Vs[j][dq*4];
                o[dq*4+0] += p * vq.x; o[dq*4+1] += p * vq.y;
                o[dq*4+2] += p * vq.z; o[dq*4+3] += p * vq.w;
            }
        }
    }

    const float inv = 1.f / ssum;
    #pragma unroll
    for (int dq = 0; dq < 8; ++dq) {
        ushort4 vh, vl;
        float v0 = o[dq*4+0]*inv, v1 = o[dq*4+1]*inv,
              v2 = o[dq*4+2]*inv, v3 = o[dq*4+3]*inv;
        u16 a0 = bf16rn(v0); vh.x = a0; vl.x = bf16rn(v0 - bf2f(a0));
        u16 a1 = bf16rn(v1); vh.y = a1; vl.y = bf16rn(v1 - bf2f(a1));
        u16 a2 = bf16rn(v2); vh.z = a2; vl.z = bf16rn(v2 - bf2f(a2));
        u16 a3 = bf16rn(v3); vh.w = a3; vl.w = bf16rn(v3 - bf2f(a3));
        const size_t a = (size_t)tid*65536
                       + (size_t)(h*4 + (dq >> 1))*2048
                       + (size_t)n*8 + (dq & 1)*4;
        *(ushort4*)(attnH + a) = vh;
        *(ushort4*)(attnL + a) = vl;
    }
}

// ---------------------------------------------------------------------------
// Wc = w_hid @ w_fc [512,256]; bc = w_hid @ b_fc + b_hid  (verified)
// ---------------------------------------------------------------------------
__global__ __launch_bounds__(256) void k_wcomb(
    const float* __restrict__ w_fc,  const float* __restrict__ b_fc,
    const float* __restrict__ w_hid, const float* __restrict__ b_hid,
    float* __restrict__ Wc, float* __restrict__ bc)
{
    const int i = blockIdx.x, j = threadIdx.x;
    float s = 0.f;
    for (int k = 0; k < FEATD; ++k) s += w_hid[i*FEATD + k] * w_fc[k*FEATD + j];
    Wc[(size_t)i*FEATD + j] = s;
    if (j == 0) {
        float t = b_hid[i];
        for (int k = 0; k < FEATD; ++k) t += w_hid[i*FEATD + k] * b_fc[k];
        bc[i] = t;
    }
}

// ---------------------------------------------------------------------------
// Wx0 = W_ih[0] @ Wc [2048,256]; bx0 = W_ih[0] @ bc + b_ih[0] + b_hh[0]
// ---------------------------------------------------------------------------
__global__ __launch_bounds__(256) void k_wx0(
    const float* __restrict__ w_ih, const float* __restrict__ Wc,
    const float* __restrict__ bc,   const float* __restrict__ b_ih,
    const float* __restrict__ b_hh,
    float* __restrict__ Wx0, float* __restrict__ bx0)
{
    const int i = blockIdx.x, j = threadIdx.x;
    float s = 0.f;
    for (int k = 0; k < HID; ++k) s += w_ih[(size_t)i*HID + k] * Wc[(size_t)k*FEATD + j];
    Wx0[(size_t)i*FEATD + j] = s;
    if (j == 0) {
        float t = b_ih[i] + b_hh[i];
        for (int k = 0; k < HID; ++k) t += w_ih[(size_t)i*HID + k] * bc[k];
        bx0[i] = t;
    }
}

// ---------------------------------------------------------------------------
// Flag-array grid barrier: parallel arrival stores (one slot per block,
// 16 cachelines) + wave-0 vectorized poll (4 relaxed agent loads/lane over
// 64 lanes = all 256 flags) + ballot. Fence structure identical to the
// verified grid_bar (release fence before arrive, acquire fence on exit).
// Flags are memset to 0 before launch; barrier n stores value n (monotonic).
// ---------------------------------------------------------------------------
__device__ __forceinline__ void flag_bar(int* flags, int step)
{
    __syncthreads();
    if (threadIdx.x == 0) {
        __threadfence();   // release: drain h stores to coherence point
        __hip_atomic_store(&flags[blockIdx.x], step,
                           __ATOMIC_RELEASE, __HIP_MEMORY_SCOPE_AGENT);
    }
    if (threadIdx.x < 64) {
        const int base = (int)threadIdx.x * 4;
        for (;;) {
            int a = __hip_atomic_load(&flags[base+0], __ATOMIC_RELAXED, __HIP_MEMORY_SCOPE_AGENT);
            int b = __hip_atomic_load(&flags[base+1], __ATOMIC_RELAXED, __HIP_MEMORY_SCOPE_AGENT);
            int c = __hip_atomic_load(&flags[base+2], __ATOMIC_RELAXED, __HIP_MEMORY_SCOPE_AGENT);
            int d = __hip_atomic_load(&flags[base+3], __ATOMIC_RELAXED, __HIP_MEMORY_SCOPE_AGENT);
            if (__all(a >= step && b >= step && c >= step && d >= step)) break;
            __builtin_amdgcn_s_sleep(8);
        }
        if (threadIdx.x == 0) __threadfence();  // acquire: invalidate L1/L2
    }
    __syncthreads();
}

// ---------------------------------------------------------------------------
struct Geo {
    const u16* wlh; const u16* wll;   // LDS weights (k-major per col)
    float* Cb;                        // LDS gate bounce [128][33]
    int rowg;                         // global batch row of A fragment
    int aq;                           // k-quarter (lane>>4)
    int boff;                         // B fragment base in wlh/wll
    int Mtile, col_local;             // C placement
    int erow, hcl;                    // epilogue row / h-col
    int cg, mg;                       // col-group, row-group
    const float* bsum;                // per-thread gate biases [4]
};

// One LSTM step. A = [s0 (NT0 slices) | s1], NT slices of K=32 total.
// srot = per-block cyclic rotation of slice order (de-synchronizes the
// same-XCD sharers' A fetches so followers hit L2; pure reorder of the
// accumulation, same products). CB8 source layout: elem (row,k) at
// (k>>3)*2048 + row*8 + (k&7). Depth-DEPTH register prefetch.
template<int NT0, int NT>
__device__ __forceinline__ void do_step(
    const Geo& G, int srot,
    const u16* __restrict__ s0H, const u16* __restrict__ s0L,
    const u16* __restrict__ s1H, const u16* __restrict__ s1L,
    u16* __restrict__ dH, u16* __restrict__ dL, float& cr)
{
    uint4 pfH[DEPTH], pfL[DEPTH];

    auto ld = [&](int d, int s) {
        int se = s + srot; if (se >= NT) se -= NT;
        const u16* pH = (se < NT0) ? s0H : s1H;
        const u16* pL = (se < NT0) ? s0L : s1L;
        const int sl  = (se < NT0) ? se : se - NT0;
        const size_t a = ((size_t)(sl*4 + G.aq) << 11) + (size_t)G.rowg * 8;
        pfH[d] = *(const uint4*)(pH + a);
        pfL[d] = *(const uint4*)(pL + a);
    };

    constexpr int PRIME = (DEPTH < NT) ? DEPTH : NT;
    #pragma unroll
    for (int d = 0; d < PRIME; ++d) ld(d, d);

    f32x4 acc = {0.f, 0.f, 0.f, 0.f};
    #pragma unroll
    for (int s = 0; s < NT; ++s) {
        U8 ua, ul;
        ua.u4 = pfH[s % DEPTH];
        ul.u4 = pfL[s % DEPTH];
        if (s + DEPTH < NT) ld(s % DEPTH, s + DEPTH);
        int se = s + srot; if (se >= NT) se -= NT;
        const short8 bh = *(const short8*)(G.wlh + G.boff + se*32);
        const short8 bl = *(const short8*)(G.wll + G.boff + se*32);
        acc = __builtin_amdgcn_mfma_f32_16x16x32_bf16(ua.s8, bh, acc, 0,0,0);
        acc = __builtin_amdgcn_mfma_f32_16x16x32_bf16(ul.s8, bh, acc, 0,0,0);
        acc = __builtin_amdgcn_mfma_f32_16x16x32_bf16(ua.s8, bl, acc, 0,0,0);
    }

    // C fragments -> LDS bounce
    {
        const int crow = G.Mtile*16 + G.aq*4;
        #pragma unroll
        for (int r = 0; r < 4; ++r)
            G.Cb[(crow + r)*33 + G.col_local] = acc[r];
    }
    __syncthreads();

    // gates + cell update + split-bf16 h store (CB8 layout, block-private)
    {
        float g4[4];
        #pragma unroll
        for (int g = 0; g < 4; ++g) g4[g] = G.Cb[G.erow*33 + g*8 + G.hcl] + G.bsum[g];
        const float gi = sigm(g4[0]), gf = sigm(g4[1]);
        const float gg = tanhfast(g4[2]), go = sigm(g4[3]);
        cr = gf*cr + gi*gg;
        const float h = go * tanhfast(cr);
        const u16 hh = bf16rn(h);
        const u16 hl = bf16rn(h - bf2f(hh));
        const size_t a = ((size_t)G.cg << 11) + (size_t)(G.mg*128 + G.erow)*8 + G.hcl;
        dH[a] = hh; dL[a] = hl;
    }
}

// ---------------------------------------------------------------------------
// Persistent MFMA LSTM. 256 blocks x 1024 threads (16 waves, 4/SIMD).
// Layer 1: blocks 0..127; layer 0: blocks 128..255. Block = (cg 0..63, mg
// 0..1): 32 gate-cols (8 h-cols = one cb8) x 128 batch rows. Weights
// split-bf16 LDS-resident. A read direct global->regs, depth-6 pipeline,
// per-block slice rotation for L2 sharing among same-XCD blocks.
// ---------------------------------------------------------------------------
__global__ __launch_bounds__(THR, 1) void k_lstm(
    const u16* __restrict__ attnH, const u16* __restrict__ attnL,
    const float* __restrict__ Wx0, const float* __restrict__ bx0,
    u16* __restrict__ h0h, u16* __restrict__ h0l,
    u16* __restrict__ h1h, u16* __restrict__ h1l,
    const float* __restrict__ w_ih, const float* __restrict__ w_hh,
    const float* __restrict__ b_ih, const float* __restrict__ b_hh,
    const float* __restrict__ w_out, const float* __restrict__ b_out,
    float* __restrict__ out, int* __restrict__ flags)
{
    extern __shared__ char smem[];
    const int tid  = threadIdx.x;
    const int bx   = blockIdx.x;
    const bool lay1 = (bx < 128);
    const int idx  = lay1 ? bx : bx - 128;
    const int cg   = idx >> 1;
    const int mg   = idx & 1;
    const int rot  = (idx >> 3) & 15;     // sharer rank among same-XCD peers
    const int KSTR = lay1 ? 1032 : 776;   // padded k-stride (halves)
    const int KW   = lay1 ? 1024 : 768;

    u16*   wlh = (u16*)smem;
    u16*   wll = wlh + 32*KSTR;
    float* Cb  = (float*)(smem + 132096);

    const int wid = tid >> 6, l = tid & 63;
    const int Mtile = wid & 7, Ntile = wid >> 3;
    const int lr = l & 15, aq = l >> 4;

    Geo G;
    G.wlh = wlh; G.wll = wll; G.Cb = Cb;
    G.rowg = mg*128 + Mtile*16 + lr;
    G.aq = aq;
    G.Mtile = Mtile;
    G.col_local = Ntile*16 + lr;
    G.boff = G.col_local*KSTR + aq*8;
    G.erow = tid & 127; G.hcl = tid >> 7;
    G.cg = cg; G.mg = mg;

    // ---- stage weights once: split fp32 -> bf16 hi/lo, k-major per col
    for (int c = 0; c < 32; ++c) {
        const int grow = (c >> 3)*HID + cg*8 + (c & 7);
        const float* src0; const float* src1; int klen0;
        if (lay1) {
            src0 = w_ih + (size_t)GATES*HID + (size_t)grow*HID; klen0 = 512;
            src1 = w_hh + (size_t)GATES*HID + (size_t)grow*HID;
        } else {
            src0 = Wx0 + (size_t)grow*FEATD;                    klen0 = 256;
            src1 = w_hh + (size_t)grow*HID;
        }
        for (int k = tid; k < KW; k += THR) {
            float f = (k < klen0) ? src0[k] : src1[k - klen0];
            u16 hi = bf16rn(f);
            wlh[c*KSTR + k] = hi;
            wll[c*KSTR + k] = bf16rn(f - bf2f(hi));
        }
    }

    float bsum[4];
    #pragma unroll
    for (int g = 0; g < 4; ++g) {
        const int gidx = g*HID + cg*8 + G.hcl;
        bsum[g] = lay1 ? (b_ih[GATES + gidx] + b_hh[GATES + gidx]) : bx0[gidx];
    }
    G.bsum = bsum;
    float cr = 0.f;
    __syncthreads();

    // projection: rows 2*idx, 2*idx+1 (layer-0 blocks only)
    auto proj = [&](const u16* hH, const u16* hL, int tout) {
        if (tid < 256) {
            const int r = tid >> 7, j = (tid >> 4) & 7, ks = tid & 15;
            const int n = 2*idx + r;
            float s = 0.f;
            #pragma unroll
            for (int kk = 0; kk < 32; ++kk) {
                const int k = ks*32 + kk;
                const size_t a = (size_t)(k >> 3)*2048 + (size_t)n*8 + (k & 7);
                float hv = bf2f(hH[a]) + bf2f(hL[a]);
                hv = hv > 0.f ? hv : 0.f;
                s += hv * w_out[(size_t)j*HID + k];
            }
            s += __shfl_xor(s, 1); s += __shfl_xor(s, 2);
            s += __shfl_xor(s, 4); s += __shfl_xor(s, 8);
            if (ks == 0)
                out[(size_t)n*(TOUT*NHEADS) + (size_t)tout*NHEADS + j] = s + b_out[j];
        }
    };

    // ---- prologue: layer0 computes h0(0) from attn(0) only
    if (!lay1)
        do_step<8,8>(G, rot >> 1, attnH, attnL, attnH, attnL, h0h, h0l, cr);
    flag_bar(flags, 1);

    // ---- pipelined: layer1(t) || layer0(t+1), t = 0..254
    for (int t = 0; t <= SEQT - 2; ++t) {
        if (lay1) {
            const int p = t & 1, q = p ^ 1;
            if (t == 0)
                do_step<16,16>(G, rot, h0h + (size_t)p*BH, h0l + (size_t)p*BH,
                                  h1h + (size_t)q*BH, h1l + (size_t)q*BH,
                                  h1h + (size_t)p*BH, h1l + (size_t)p*BH, cr);
            else
                do_step<16,32>(G, rot*2, h0h + (size_t)p*BH, h0l + (size_t)p*BH,
                                  h1h + (size_t)q*BH, h1l + (size_t)q*BH,
                                  h1h + (size_t)p*BH, h1l + (size_t)p*BH, cr);
        } else {
            if (t >= 1) {
                const int q = (t - 1) & 1;
                proj(h1h + (size_t)q*BH, h1l + (size_t)q*BH, t - 1);
            }
            if (t <= SEQT - 3) {
                const int tt = t + 1, p = t & 1, d = tt & 1;
                do_step<8,24>(G, (rot*3) >> 1,
                                 attnH + (size_t)tt*65536, attnL + (size_t)tt*65536,
                                 h0h + (size_t)p*BH, h0l + (size_t)p*BH,
                                 h0h + (size_t)d*BH, h0l + (size_t)d*BH, cr);
            }
        }
        flag_bar(flags, t + 2);
    }

    // ---- tail: project h1(254) (parity 0)
    if (!lay1) proj(h1h, h1l, TOUT - 1);
}

// ---------------------------------------------------------------------------
extern "C" void kernel_launch(void* const* d_in, const int* in_sizes, int n_in,
                              void* d_out, int out_size, void* d_ws, size_t ws_size,
                              hipStream_t stream)
{
    (void)in_sizes; (void)n_in; (void)out_size; (void)ws_size;
    const float* x     = (const float*)d_in[0];
    const float* wq    = (const float*)d_in[1];
    const float* wk    = (const float*)d_in[2];
    const float* wv    = (const float*)d_in[3];
    const float* w_fc  = (const float*)d_in[4];
    const float* b_fc  = (const float*)d_in[5];
    const float* w_hid = (const float*)d_in[6];
    const float* b_hid = (const float*)d_in[7];
    const float* w_ih  = (const float*)d_in[8];
    const float* w_hh  = (const float*)d_in[9];
    const float* b_ih  = (const float*)d_in[10];
    const float* b_hh  = (const float*)d_in[11];
    const float* w_out = (const float*)d_in[12];
    const float* b_out = (const float*)d_in[13];

    float* ws = (float*)d_ws;
    size_t off = 0;
    u16* attnH = (u16*)(ws + off); off += (size_t)SEQT*BATCH*FEATD/2;
    u16* attnL = (u16*)(ws + off); off += (size_t)SEQT*BATCH*FEATD/2;
    float* Wc  = ws + off; off += (size_t)HID*FEATD;
    float* bc  = ws + off; off += HID;
    float* Wx0 = ws + off; off += (size_t)GATES*FEATD;
    float* bx0 = ws + off; off += GATES;
    u16* h0h = (u16*)(ws + off); off += BH;    // 2 parity slabs (BH halves each)
    u16* h0l = (u16*)(ws + off); off += BH;
    u16* h1h = (u16*)(ws + off); off += BH;
    u16* h1l = (u16*)(ws + off); off += BH;
    int* flags = (int*)(ws + off); off += 256;

    hipMemsetAsync(flags, 0, NBLK*sizeof(int), stream);

    k_attn  <<<dim3(BATCH*NHEADS), dim3(256), 0, stream>>>(x, wq, wk, wv, attnH, attnL);
    k_wcomb <<<dim3(HID),          dim3(256), 0, stream>>>(w_fc, b_fc, w_hid, b_hid, Wc, bc);
    k_wx0   <<<dim3(GATES),        dim3(256), 0, stream>>>(w_ih, Wc, bc, b_ih, b_hh, Wx0, bx0);

    const int shmem = 132096 + 128*33*4;   // weights (L1 max) + Cb = 148992 B
    (void)hipFuncSetAttribute(reinterpret_cast<const void*>(k_lstm),
                              hipFuncAttributeMaxDynamicSharedMemorySize, shmem);
    k_lstm <<<dim3(NBLK), dim3(THR), (size_t)shmem, stream>>>(
        attnH, attnL, Wx0, bx0, h0h, h0l, h1h, h1l,
        w_ih, w_hh, b_ih, b_hh, w_out, b_out, (float*)d_out, flags);
}

// Round 9
// 9856.606 us; speedup vs baseline: 1.6605x; 1.6514x over previous
//
#include <hip/hip_runtime.h>
#include <math.h>

// Problem constants
#define BATCH  256
#define SEQT   256
#define FEATD  256
#define NHEADS 8
#define HD     32
#define HID    512
#define GATES  2048
#define BH     (BATCH*HID)       // halves per h plane parity slab
#define TOUT   (SEQT-1)
#define NBLK   256
#define THR    1024
#define DEPTH  6                 // prefetch depth (slices)

typedef __attribute__((ext_vector_type(8))) short short8;
typedef __attribute__((ext_vector_type(4))) float f32x4;
typedef unsigned short u16;

union U8 { uint4 u4; short8 s8; };

__device__ __forceinline__ float sigm(float x)     { return 1.f / (1.f + __expf(-x)); }
__device__ __forceinline__ float tanhfast(float x) { return 1.f - 2.f / (1.f + __expf(2.f * x)); }

__device__ __forceinline__ u16 bf16rn(float f) {
    union { float f; unsigned u; } v; v.f = f;
    unsigned r = v.u + 0x7fffu + ((v.u >> 16) & 1u);
    return (u16)(r >> 16);
}
__device__ __forceinline__ float bf2f(u16 h) {
    union { float f; unsigned u; } v; v.u = ((unsigned)h) << 16; return v.f;
}

// ---------------------------------------------------------------------------
// Fused per-(n,h) attention (verified). Output T-major CB8 layout:
// attn[t][cb8=f/8][n][8] split bf16 hi/lo planes (65536 halves per t-slice).
// ---------------------------------------------------------------------------
__global__ __launch_bounds__(256) void k_attn(
    const float* __restrict__ x,  const float* __restrict__ wq,
    const float* __restrict__ wk, const float* __restrict__ wv,
    u16* __restrict__ attnH, u16* __restrict__ attnL)
{
    __shared__ float Ks[128][40];
    __shared__ float Vs[128][40];

    const int nb  = blockIdx.x;
    const int n   = nb >> 3, h = nb & 7;
    const int tid = threadIdx.x;
    const float* xbase = x + ((size_t)n * SEQT) * FEATD + h * HD;

    float qv[HD];
    {
        float xr[HD];
        const float4* xp = (const float4*)(xbase + (size_t)tid * FEATD);
        #pragma unroll
        for (int q4 = 0; q4 < 8; ++q4) {
            float4 v = xp[q4];
            xr[q4*4+0] = v.x; xr[q4*4+1] = v.y; xr[q4*4+2] = v.z; xr[q4*4+3] = v.w;
        }
        #pragma unroll
        for (int d = 0; d < HD; ++d) {
            float s = 0.f;
            #pragma unroll
            for (int e = 0; e < HD; ++e) s += xr[e] * wq[d*HD + e];
            qv[d] = s * 0.0625f;
        }
    }

    float o[HD];
    #pragma unroll
    for (int d = 0; d < HD; ++d) o[d] = 0.f;
    float m = -1e30f, ssum = 0.f;

    for (int tile = 0; tile < 2; ++tile) {
        const int j0 = tile * 128;
        __syncthreads();
        {
            const int r = tid & 127;
            const float* W = (tid < 128) ? wk : wv;
            float xt[HD];
            const float4* xp = (const float4*)(xbase + (size_t)(j0 + r) * FEATD);
            #pragma unroll
            for (int q4 = 0; q4 < 8; ++q4) {
                float4 v = xp[q4];
                xt[q4*4+0] = v.x; xt[q4*4+1] = v.y; xt[q4*4+2] = v.z; xt[q4*4+3] = v.w;
            }
            float outr[HD];
            #pragma unroll
            for (int d = 0; d < HD; ++d) {
                float s = 0.f;
                #pragma unroll
                for (int e = 0; e < HD; ++e) s += xt[e] * W[d*HD + e];
                outr[d] = s;
            }
            float (*dst)[40] = (tid < 128) ? Ks : Vs;
            #pragma unroll
            for (int d = 0; d < HD; ++d) dst[r][d] = outr[d];
        }
        __syncthreads();

        for (int j = 0; j < 128; ++j) {
            float e = 0.f;
            #pragma unroll
            for (int dq = 0; dq < 8; ++dq) {
                float4 kq = *(const float4*)&Ks[j][dq*4];
                e += qv[dq*4+0]*kq.x + qv[dq*4+1]*kq.y
                   + qv[dq*4+2]*kq.z + qv[dq*4+3]*kq.w;
            }
            if (e > m) {
                float sc = __expf(m - e);
                ssum *= sc;
                #pragma unroll
                for (int d = 0; d < HD; ++d) o[d] *= sc;
                m = e;
            }
            float p = __expf(e - m);
            ssum += p;
            #pragma unroll
            for (int dq = 0; dq < 8; ++dq) {
                float4 vq = *(const float4*)&Vs[j][dq*4];
                o[dq*4+0] += p * vq.x; o[dq*4+1] += p * vq.y;
                o[dq*4+2] += p * vq.z; o[dq*4+3] += p * vq.w;
            }
        }
    }

    const float inv = 1.f / ssum;
    #pragma unroll
    for (int dq = 0; dq < 8; ++dq) {
        ushort4 vh, vl;
        float v0 = o[dq*4+0]*inv, v1 = o[dq*4+1]*inv,
              v2 = o[dq*4+2]*inv, v3 = o[dq*4+3]*inv;
        u16 a0 = bf16rn(v0); vh.x = a0; vl.x = bf16rn(v0 - bf2f(a0));
        u16 a1 = bf16rn(v1); vh.y = a1; vl.y = bf16rn(v1 - bf2f(a1));
        u16 a2 = bf16rn(v2); vh.z = a2; vl.z = bf16rn(v2 - bf2f(a2));
        u16 a3 = bf16rn(v3); vh.w = a3; vl.w = bf16rn(v3 - bf2f(a3));
        const size_t a = (size_t)tid*65536
                       + (size_t)(h*4 + (dq >> 1))*2048
                       + (size_t)n*8 + (dq & 1)*4;
        *(ushort4*)(attnH + a) = vh;
        *(ushort4*)(attnL + a) = vl;
    }
}

// ---------------------------------------------------------------------------
// Wc = w_hid @ w_fc [512,256]; bc = w_hid @ b_fc + b_hid  (verified)
// ---------------------------------------------------------------------------
__global__ __launch_bounds__(256) void k_wcomb(
    const float* __restrict__ w_fc,  const float* __restrict__ b_fc,
    const float* __restrict__ w_hid, const float* __restrict__ b_hid,
    float* __restrict__ Wc, float* __restrict__ bc)
{
    const int i = blockIdx.x, j = threadIdx.x;
    float s = 0.f;
    for (int k = 0; k < FEATD; ++k) s += w_hid[i*FEATD + k] * w_fc[k*FEATD + j];
    Wc[(size_t)i*FEATD + j] = s;
    if (j == 0) {
        float t = b_hid[i];
        for (int k = 0; k < FEATD; ++k) t += w_hid[i*FEATD + k] * b_fc[k];
        bc[i] = t;
    }
}

// ---------------------------------------------------------------------------
// Wx0 = W_ih[0] @ Wc [2048,256]; bx0 = W_ih[0] @ bc + b_ih[0] + b_hh[0]
// ---------------------------------------------------------------------------
__global__ __launch_bounds__(256) void k_wx0(
    const float* __restrict__ w_ih, const float* __restrict__ Wc,
    const float* __restrict__ bc,   const float* __restrict__ b_ih,
    const float* __restrict__ b_hh,
    float* __restrict__ Wx0, float* __restrict__ bx0)
{
    const int i = blockIdx.x, j = threadIdx.x;
    float s = 0.f;
    for (int k = 0; k < HID; ++k) s += w_ih[(size_t)i*HID + k] * Wc[(size_t)k*FEATD + j];
    Wx0[(size_t)i*FEATD + j] = s;
    if (j == 0) {
        float t = b_ih[i] + b_hh[i];
        for (int k = 0; k < HID; ++k) t += w_ih[(size_t)i*HID + k] * bc[k];
        bx0[i] = t;
    }
}

// ---------------------------------------------------------------------------
// Hybrid grid barrier:
//   arrive  : parallel release-store, one flag slot per block (no RMW chain)
//   aggr    : block 0 only scans all 256 flags, publishes one epoch word
//   wait    : every block polls the single epoch word (1 load/iter)
// Fence structure identical to the verified rounds-3..6 barrier.
// ---------------------------------------------------------------------------
__device__ __forceinline__ void hybrid_bar(int* flags, int* epoch, int step)
{
    __syncthreads();
    if (threadIdx.x == 0) {
        __threadfence();   // release: h stores to coherence point first
        __hip_atomic_store(&flags[blockIdx.x], step,
                           __ATOMIC_RELEASE, __HIP_MEMORY_SCOPE_AGENT);
    }
    if (blockIdx.x == 0 && threadIdx.x < 64) {
        const int base = (int)threadIdx.x * 4;
        for (;;) {
            int a = __hip_atomic_load(&flags[base+0], __ATOMIC_RELAXED, __HIP_MEMORY_SCOPE_AGENT);
            int b = __hip_atomic_load(&flags[base+1], __ATOMIC_RELAXED, __HIP_MEMORY_SCOPE_AGENT);
            int c = __hip_atomic_load(&flags[base+2], __ATOMIC_RELAXED, __HIP_MEMORY_SCOPE_AGENT);
            int d = __hip_atomic_load(&flags[base+3], __ATOMIC_RELAXED, __HIP_MEMORY_SCOPE_AGENT);
            if (__all(a >= step && b >= step && c >= step && d >= step)) break;
            __builtin_amdgcn_s_sleep(2);
        }
        if (threadIdx.x == 0)
            __hip_atomic_store(epoch, step,
                               __ATOMIC_RELEASE, __HIP_MEMORY_SCOPE_AGENT);
    }
    if (threadIdx.x == 0) {
        while (__hip_atomic_load(epoch, __ATOMIC_RELAXED, __HIP_MEMORY_SCOPE_AGENT) < step)
            __builtin_amdgcn_s_sleep(2);
        __threadfence();   // acquire: invalidate stale cached h
    }
    __syncthreads();
}

// ---------------------------------------------------------------------------
struct Geo {
    const u16* wlh; const u16* wll;   // LDS weights (k-major per col)
    float* Cb;                        // LDS gate bounce [128][33]
    int rowg;                         // global batch row of A fragment
    int aq;                           // k-quarter (lane>>4)
    int boff;                         // B fragment base in wlh/wll
    int Mtile, col_local;             // C placement
    int erow, hcl;                    // epilogue row / h-col
    int cg, mg;                       // col-group, row-group
    const float* bsum;                // per-thread gate biases [4]
};

// One LSTM step. A = [s0 (NT0 slices) | s1], NT slices of K=32 total.
// CB8 source layout: elem (row,k) at (k>>3)*2048 + row*8 + (k&7).
// Depth-DEPTH register prefetch (verified R6 core, bit-identical math).
template<int NT0, int NT>
__device__ __forceinline__ void do_step(
    const Geo& G,
    const u16* __restrict__ s0H, const u16* __restrict__ s0L,
    const u16* __restrict__ s1H, const u16* __restrict__ s1L,
    u16* __restrict__ dH, u16* __restrict__ dL, float& cr)
{
    uint4 pfH[DEPTH], pfL[DEPTH];

    auto ld = [&](int d, int s) {
        const u16* pH = (s < NT0) ? s0H : s1H;
        const u16* pL = (s < NT0) ? s0L : s1L;
        const int sl  = (s < NT0) ? s : s - NT0;
        const size_t a = ((size_t)(sl*4 + G.aq) << 11) + (size_t)G.rowg * 8;
        pfH[d] = *(const uint4*)(pH + a);
        pfL[d] = *(const uint4*)(pL + a);
    };

    constexpr int PRIME = (DEPTH < NT) ? DEPTH : NT;
    #pragma unroll
    for (int d = 0; d < PRIME; ++d) ld(d, d);

    f32x4 acc = {0.f, 0.f, 0.f, 0.f};
    #pragma unroll
    for (int s = 0; s < NT; ++s) {
        U8 ua, ul;
        ua.u4 = pfH[s % DEPTH];
        ul.u4 = pfL[s % DEPTH];
        if (s + DEPTH < NT) ld(s % DEPTH, s + DEPTH);
        const short8 bh = *(const short8*)(G.wlh + G.boff + s*32);
        const short8 bl = *(const short8*)(G.wll + G.boff + s*32);
        acc = __builtin_amdgcn_mfma_f32_16x16x32_bf16(ua.s8, bh, acc, 0,0,0);
        acc = __builtin_amdgcn_mfma_f32_16x16x32_bf16(ul.s8, bh, acc, 0,0,0);
        acc = __builtin_amdgcn_mfma_f32_16x16x32_bf16(ua.s8, bl, acc, 0,0,0);
    }

    // C fragments -> LDS bounce
    {
        const int crow = G.Mtile*16 + G.aq*4;
        #pragma unroll
        for (int r = 0; r < 4; ++r)
            G.Cb[(crow + r)*33 + G.col_local] = acc[r];
    }
    __syncthreads();

    // gates + cell update + split-bf16 h store (CB8 layout, block-private)
    {
        float g4[4];
        #pragma unroll
        for (int g = 0; g < 4; ++g) g4[g] = G.Cb[G.erow*33 + g*8 + G.hcl] + G.bsum[g];
        const float gi = sigm(g4[0]), gf = sigm(g4[1]);
        const float gg = tanhfast(g4[2]), go = sigm(g4[3]);
        cr = gf*cr + gi*gg;
        const float h = go * tanhfast(cr);
        const u16 hh = bf16rn(h);
        const u16 hl = bf16rn(h - bf2f(hh));
        const size_t a = ((size_t)G.cg << 11) + (size_t)(G.mg*128 + G.erow)*8 + G.hcl;
        dH[a] = hh; dL[a] = hl;
    }
}

// ---------------------------------------------------------------------------
// Persistent MFMA LSTM. 256 blocks x 1024 threads (16 waves, 4/SIMD).
// Layer 1: blocks 0..127; layer 0: blocks 128..255. Block = (cg 0..63, mg
// 0..1): 32 gate-cols (8 h-cols = one cb8) x 128 batch rows. Weights
// split-bf16 LDS-resident. A read direct global->regs, depth-6 pipeline.
// Hybrid barrier (flag-array arrive, single aggregator, 1-word poll).
// ---------------------------------------------------------------------------
__global__ __launch_bounds__(THR, 1) void k_lstm(
    const u16* __restrict__ attnH, const u16* __restrict__ attnL,
    const float* __restrict__ Wx0, const float* __restrict__ bx0,
    u16* __restrict__ h0h, u16* __restrict__ h0l,
    u16* __restrict__ h1h, u16* __restrict__ h1l,
    const float* __restrict__ w_ih, const float* __restrict__ w_hh,
    const float* __restrict__ b_ih, const float* __restrict__ b_hh,
    const float* __restrict__ w_out, const float* __restrict__ b_out,
    float* __restrict__ out, int* __restrict__ flags, int* __restrict__ epoch)
{
    extern __shared__ char smem[];
    const int tid  = threadIdx.x;
    const int bx   = blockIdx.x;
    const bool lay1 = (bx < 128);
    const int idx  = lay1 ? bx : bx - 128;
    const int cg   = idx >> 1;
    const int mg   = idx & 1;
    const int KSTR = lay1 ? 1032 : 776;   // padded k-stride (halves)
    const int KW   = lay1 ? 1024 : 768;

    u16*   wlh = (u16*)smem;
    u16*   wll = wlh + 32*KSTR;
    float* Cb  = (float*)(smem + 132096);

    const int wid = tid >> 6, l = tid & 63;
    const int Mtile = wid & 7, Ntile = wid >> 3;
    const int lr = l & 15, aq = l >> 4;

    Geo G;
    G.wlh = wlh; G.wll = wll; G.Cb = Cb;
    G.rowg = mg*128 + Mtile*16 + lr;
    G.aq = aq;
    G.Mtile = Mtile;
    G.col_local = Ntile*16 + lr;
    G.boff = G.col_local*KSTR + aq*8;
    G.erow = tid & 127; G.hcl = tid >> 7;
    G.cg = cg; G.mg = mg;

    // ---- stage weights once: split fp32 -> bf16 hi/lo, k-major per col
    for (int c = 0; c < 32; ++c) {
        const int grow = (c >> 3)*HID + cg*8 + (c & 7);
        const float* src0; const float* src1; int klen0;
        if (lay1) {
            src0 = w_ih + (size_t)GATES*HID + (size_t)grow*HID; klen0 = 512;
            src1 = w_hh + (size_t)GATES*HID + (size_t)grow*HID;
        } else {
            src0 = Wx0 + (size_t)grow*FEATD;                    klen0 = 256;
            src1 = w_hh + (size_t)grow*HID;
        }
        for (int k = tid; k < KW; k += THR) {
            float f = (k < klen0) ? src0[k] : src1[k - klen0];
            u16 hi = bf16rn(f);
            wlh[c*KSTR + k] = hi;
            wll[c*KSTR + k] = bf16rn(f - bf2f(hi));
        }
    }

    float bsum[4];
    #pragma unroll
    for (int g = 0; g < 4; ++g) {
        const int gidx = g*HID + cg*8 + G.hcl;
        bsum[g] = lay1 ? (b_ih[GATES + gidx] + b_hh[GATES + gidx]) : bx0[gidx];
    }
    G.bsum = bsum;
    float cr = 0.f;
    __syncthreads();

    // projection: rows 2*idx, 2*idx+1 (layer-0 blocks only)
    auto proj = [&](const u16* hH, const u16* hL, int tout) {
        if (tid < 256) {
            const int r = tid >> 7, j = (tid >> 4) & 7, ks = tid & 15;
            const int n = 2*idx + r;
            float s = 0.f;
            #pragma unroll
            for (int kk = 0; kk < 32; ++kk) {
                const int k = ks*32 + kk;
                const size_t a = (size_t)(k >> 3)*2048 + (size_t)n*8 + (k & 7);
                float hv = bf2f(hH[a]) + bf2f(hL[a]);
                hv = hv > 0.f ? hv : 0.f;
                s += hv * w_out[(size_t)j*HID + k];
            }
            s += __shfl_xor(s, 1); s += __shfl_xor(s, 2);
            s += __shfl_xor(s, 4); s += __shfl_xor(s, 8);
            if (ks == 0)
                out[(size_t)n*(TOUT*NHEADS) + (size_t)tout*NHEADS + j] = s + b_out[j];
        }
    };

    // ---- prologue: layer0 computes h0(0) from attn(0) only
    if (!lay1)
        do_step<8,8>(G, attnH, attnL, attnH, attnL, h0h, h0l, cr);
    hybrid_bar(flags, epoch, 1);

    // ---- pipelined: layer1(t) || layer0(t+1), t = 0..254
    for (int t = 0; t <= SEQT - 2; ++t) {
        if (lay1) {
            const int p = t & 1, q = p ^ 1;
            if (t == 0)
                do_step<16,16>(G, h0h + (size_t)p*BH, h0l + (size_t)p*BH,
                                  h1h + (size_t)q*BH, h1l + (size_t)q*BH,
                                  h1h + (size_t)p*BH, h1l + (size_t)p*BH, cr);
            else
                do_step<16,32>(G, h0h + (size_t)p*BH, h0l + (size_t)p*BH,
                                  h1h + (size_t)q*BH, h1l + (size_t)q*BH,
                                  h1h + (size_t)p*BH, h1l + (size_t)p*BH, cr);
        } else {
            if (t >= 1) {
                const int q = (t - 1) & 1;
                proj(h1h + (size_t)q*BH, h1l + (size_t)q*BH, t - 1);
            }
            if (t <= SEQT - 3) {
                const int tt = t + 1, p = t & 1, d = tt & 1;
                do_step<8,24>(G, attnH + (size_t)tt*65536, attnL + (size_t)tt*65536,
                                 h0h + (size_t)p*BH, h0l + (size_t)p*BH,
                                 h0h + (size_t)d*BH, h0l + (size_t)d*BH, cr);
            }
        }
        hybrid_bar(flags, epoch, t + 2);
    }

    // ---- tail: project h1(254) (parity 0)
    if (!lay1) proj(h1h, h1l, TOUT - 1);
}

// ---------------------------------------------------------------------------
extern "C" void kernel_launch(void* const* d_in, const int* in_sizes, int n_in,
                              void* d_out, int out_size, void* d_ws, size_t ws_size,
                              hipStream_t stream)
{
    (void)in_sizes; (void)n_in; (void)out_size; (void)ws_size;
    const float* x     = (const float*)d_in[0];
    const float* wq    = (const float*)d_in[1];
    const float* wk    = (const float*)d_in[2];
    const float* wv    = (const float*)d_in[3];
    const float* w_fc  = (const float*)d_in[4];
    const float* b_fc  = (const float*)d_in[5];
    const float* w_hid = (const float*)d_in[6];
    const float* b_hid = (const float*)d_in[7];
    const float* w_ih  = (const float*)d_in[8];
    const float* w_hh  = (const float*)d_in[9];
    const float* b_ih  = (const float*)d_in[10];
    const float* b_hh  = (const float*)d_in[11];
    const float* w_out = (const float*)d_in[12];
    const float* b_out = (const float*)d_in[13];

    float* ws = (float*)d_ws;
    size_t off = 0;
    u16* attnH = (u16*)(ws + off); off += (size_t)SEQT*BATCH*FEATD/2;
    u16* attnL = (u16*)(ws + off); off += (size_t)SEQT*BATCH*FEATD/2;
    float* Wc  = ws + off; off += (size_t)HID*FEATD;
    float* bc  = ws + off; off += HID;
    float* Wx0 = ws + off; off += (size_t)GATES*FEATD;
    float* bx0 = ws + off; off += GATES;
    u16* h0h = (u16*)(ws + off); off += BH;    // 2 parity slabs (BH halves each)
    u16* h0l = (u16*)(ws + off); off += BH;
    u16* h1h = (u16*)(ws + off); off += BH;
    u16* h1l = (u16*)(ws + off); off += BH;
    int* flags = (int*)(ws + off); off += 256;  // 256 flag slots
    int* epoch = (int*)(ws + off); off += 64;   // own cacheline

    hipMemsetAsync(flags, 0, (NBLK + 64)*sizeof(int), stream);

    k_attn  <<<dim3(BATCH*NHEADS), dim3(256), 0, stream>>>(x, wq, wk, wv, attnH, attnL);
    k_wcomb <<<dim3(HID),          dim3(256), 0, stream>>>(w_fc, b_fc, w_hid, b_hid, Wc, bc);
    k_wx0   <<<dim3(GATES),        dim3(256), 0, stream>>>(w_ih, Wc, bc, b_ih, b_hh, Wx0, bx0);

    const int shmem = 132096 + 128*33*4;   // weights (L1 max) + Cb = 148992 B
    (void)hipFuncSetAttribute(reinterpret_cast<const void*>(k_lstm),
                              hipFuncAttributeMaxDynamicSharedMemorySize, shmem);
    k_lstm <<<dim3(NBLK), dim3(THR), (size_t)shmem, stream>>>(
        attnH, attnL, Wx0, bx0, h0h, h0l, h1h, h1l,
        w_ih, w_hh, b_ih, b_hh, w_out, b_out, (float*)d_out, flags, epoch);
}